// Round 1
// baseline (242.324 us; speedup 1.0000x reference)
//
#include <hip/hip_runtime.h>

#define BB 128
#define FF 512

// One 64-lane wave per (b,j) row of hebb. Each lane owns 8 floats of the
// 512-float row (two float4 segments at k = lane*4 and k = 256 + lane*4).
// Pass 1 (registers): acc += last_out[k] * (weight[j,k] + ps[j,k]*hebb[b,j,k])
// xor-butterfly reduce -> all lanes hold pre[b,j]; out = tanh(pre + input).
// Pass 2 (same registers): hebb_new = fma(lr*out, last_out[k] - out*hebb, hebb).
// hebb is read once and hebb_new written once -> pure HBM roofline (~269 MB).
__global__ __launch_bounds__(256) void PlasticLinearRec_kernel(
    const float* __restrict__ input,
    const float* __restrict__ last_out,
    const float* __restrict__ hebb,
    const float* __restrict__ weight,
    const float* __restrict__ ps,
    const float* __restrict__ lr_p,
    float* __restrict__ out,       // B*F
    float* __restrict__ hebb_new)  // B*F*F
{
    const int wave = threadIdx.x >> 6;          // 4 waves / block
    const int lane = threadIdx.x & 63;
    const int row  = blockIdx.x * 4 + wave;     // 0 .. B*F-1
    const int b    = row >> 9;                  // row / F
    const int j    = row & (FF - 1);            // row % F

    const size_t hbase  = (size_t)row * FF;     // hebb[b, j, :]
    const int    wbase  = j * FF;               // weight/ps[j, :]
    const int    lobase = b * FF;               // last_out/input[b, :]

    const int k0 = lane * 4;
    const int k1 = 256 + lane * 4;

    const float4 h0 = *(const float4*)(hebb     + hbase  + k0);
    const float4 h1 = *(const float4*)(hebb     + hbase  + k1);
    const float4 w0 = *(const float4*)(weight   + wbase  + k0);
    const float4 w1 = *(const float4*)(weight   + wbase  + k1);
    const float4 p0 = *(const float4*)(ps       + wbase  + k0);
    const float4 p1 = *(const float4*)(ps       + wbase  + k1);
    const float4 l0 = *(const float4*)(last_out + lobase + k0);
    const float4 l1 = *(const float4*)(last_out + lobase + k1);

    float acc = 0.0f;
    acc = fmaf(l0.x, fmaf(p0.x, h0.x, w0.x), acc);
    acc = fmaf(l0.y, fmaf(p0.y, h0.y, w0.y), acc);
    acc = fmaf(l0.z, fmaf(p0.z, h0.z, w0.z), acc);
    acc = fmaf(l0.w, fmaf(p0.w, h0.w, w0.w), acc);
    acc = fmaf(l1.x, fmaf(p1.x, h1.x, w1.x), acc);
    acc = fmaf(l1.y, fmaf(p1.y, h1.y, w1.y), acc);
    acc = fmaf(l1.z, fmaf(p1.z, h1.z, w1.z), acc);
    acc = fmaf(l1.w, fmaf(p1.w, h1.w, w1.w), acc);

    // 64-lane xor butterfly: every lane ends with the full row sum.
    #pragma unroll
    for (int off = 32; off > 0; off >>= 1)
        acc += __shfl_xor(acc, off, 64);

    const float o = tanhf(acc + input[lobase + j]);
    const float c = lr_p[0] * o;   // lr * out[b,j]

    if (lane == 0) out[lobase + j] = o;

    float4 n0, n1;
    n0.x = fmaf(c, l0.x - o * h0.x, h0.x);
    n0.y = fmaf(c, l0.y - o * h0.y, h0.y);
    n0.z = fmaf(c, l0.z - o * h0.z, h0.z);
    n0.w = fmaf(c, l0.w - o * h0.w, h0.w);
    n1.x = fmaf(c, l1.x - o * h1.x, h1.x);
    n1.y = fmaf(c, l1.y - o * h1.y, h1.y);
    n1.z = fmaf(c, l1.z - o * h1.z, h1.z);
    n1.w = fmaf(c, l1.w - o * h1.w, h1.w);

    *(float4*)(hebb_new + hbase + k0) = n0;
    *(float4*)(hebb_new + hbase + k1) = n1;
}

extern "C" void kernel_launch(void* const* d_in, const int* in_sizes, int n_in,
                              void* d_out, int out_size, void* d_ws, size_t ws_size,
                              hipStream_t stream) {
    const float* input    = (const float*)d_in[0];
    const float* last_out = (const float*)d_in[1];
    const float* hebb     = (const float*)d_in[2];
    const float* weight   = (const float*)d_in[3];
    const float* ps       = (const float*)d_in[4];
    const float* lr       = (const float*)d_in[5];

    float* out      = (float*)d_out;            // first B*F floats
    float* hebb_new = out + BB * FF;            // then B*F*F floats

    const int rows   = BB * FF;                 // 65536 rows
    const int blocks = rows / 4;                // 4 waves (rows) per 256-thr block

    PlasticLinearRec_kernel<<<blocks, 256, 0, stream>>>(
        input, last_out, hebb, weight, ps, lr, out, hebb_new);
}

// Round 3
// 241.507 us; speedup vs baseline: 1.0034x; 1.0034x over previous
//
#include <hip/hip_runtime.h>

#define BB 128
#define FF 512

// Native clang vector type — required by __builtin_nontemporal_{load,store}
// (HIP's float4 is a struct wrapper and is rejected).
typedef float v4f __attribute__((ext_vector_type(4)));

// One 64-lane wave per (b,j) row of hebb. Each lane owns 8 floats of the
// 512-float row (two float4 segments at k = lane*4 and k = 256 + lane*4).
// Pass 1 (registers): acc += last_out[k] * (weight[j,k] + ps[j,k]*hebb[b,j,k])
// xor-butterfly reduce -> all lanes hold pre[b,j]; out = tanh(pre + input).
// Pass 2 (same registers): hebb_new = fma(lr*out, last_out[k] - out*hebb, hebb).
// hebb read once (nontemporal: no reuse, keep L2 for weight/ps), hebb_new
// written once (nontemporal streaming store) -> pure HBM roofline (~269 MB).
__global__ __launch_bounds__(256) void PlasticLinearRec_kernel(
    const float* __restrict__ input,
    const float* __restrict__ last_out,
    const float* __restrict__ hebb,
    const float* __restrict__ weight,
    const float* __restrict__ ps,
    const float* __restrict__ lr_p,
    float* __restrict__ out,       // B*F
    float* __restrict__ hebb_new)  // B*F*F
{
    const int wave = threadIdx.x >> 6;          // 4 waves / block
    const int lane = threadIdx.x & 63;
    const int row  = blockIdx.x * 4 + wave;     // 0 .. B*F-1
    const int b    = row >> 9;                  // row / F
    const int j    = row & (FF - 1);            // row % F

    const size_t hbase  = (size_t)row * FF;     // hebb[b, j, :]
    const int    wbase  = j * FF;               // weight/ps[j, :]
    const int    lobase = b * FF;               // last_out/input[b, :]

    const int k0 = lane * 4;
    const int k1 = 256 + lane * 4;

    // Streaming (zero-reuse) traffic: nontemporal to bypass/minimize L2 churn.
    const v4f h0 = __builtin_nontemporal_load((const v4f*)(hebb + hbase + k0));
    const v4f h1 = __builtin_nontemporal_load((const v4f*)(hebb + hbase + k1));
    // Reused traffic (128x across b): normal cached loads, lives in L2.
    const v4f w0 = *(const v4f*)(weight   + wbase  + k0);
    const v4f w1 = *(const v4f*)(weight   + wbase  + k1);
    const v4f p0 = *(const v4f*)(ps       + wbase  + k0);
    const v4f p1 = *(const v4f*)(ps       + wbase  + k1);
    const v4f l0 = *(const v4f*)(last_out + lobase + k0);
    const v4f l1 = *(const v4f*)(last_out + lobase + k1);

    float acc = 0.0f;
    acc = fmaf(l0.x, fmaf(p0.x, h0.x, w0.x), acc);
    acc = fmaf(l0.y, fmaf(p0.y, h0.y, w0.y), acc);
    acc = fmaf(l0.z, fmaf(p0.z, h0.z, w0.z), acc);
    acc = fmaf(l0.w, fmaf(p0.w, h0.w, w0.w), acc);
    acc = fmaf(l1.x, fmaf(p1.x, h1.x, w1.x), acc);
    acc = fmaf(l1.y, fmaf(p1.y, h1.y, w1.y), acc);
    acc = fmaf(l1.z, fmaf(p1.z, h1.z, w1.z), acc);
    acc = fmaf(l1.w, fmaf(p1.w, h1.w, w1.w), acc);

    // 64-lane xor butterfly: every lane ends with the full row sum.
    #pragma unroll
    for (int off = 32; off > 0; off >>= 1)
        acc += __shfl_xor(acc, off, 64);

    const float o = tanhf(acc + input[lobase + j]);
    const float c = lr_p[0] * o;   // lr * out[b,j]

    if (lane == 0) out[lobase + j] = o;

    v4f n0, n1;
    n0.x = fmaf(c, l0.x - o * h0.x, h0.x);
    n0.y = fmaf(c, l0.y - o * h0.y, h0.y);
    n0.z = fmaf(c, l0.z - o * h0.z, h0.z);
    n0.w = fmaf(c, l0.w - o * h0.w, h0.w);
    n1.x = fmaf(c, l1.x - o * h1.x, h1.x);
    n1.y = fmaf(c, l1.y - o * h1.y, h1.y);
    n1.z = fmaf(c, l1.z - o * h1.z, h1.z);
    n1.w = fmaf(c, l1.w - o * h1.w, h1.w);

    __builtin_nontemporal_store(n0, (v4f*)(hebb_new + hbase + k0));
    __builtin_nontemporal_store(n1, (v4f*)(hebb_new + hbase + k1));
}

extern "C" void kernel_launch(void* const* d_in, const int* in_sizes, int n_in,
                              void* d_out, int out_size, void* d_ws, size_t ws_size,
                              hipStream_t stream) {
    const float* input    = (const float*)d_in[0];
    const float* last_out = (const float*)d_in[1];
    const float* hebb     = (const float*)d_in[2];
    const float* weight   = (const float*)d_in[3];
    const float* ps       = (const float*)d_in[4];
    const float* lr       = (const float*)d_in[5];

    float* out      = (float*)d_out;            // first B*F floats
    float* hebb_new = out + BB * FF;            // then B*F*F floats

    const int rows   = BB * FF;                 // 65536 rows
    const int blocks = rows / 4;                // 4 waves (rows) per 256-thr block

    PlasticLinearRec_kernel<<<blocks, 256, 0, stream>>>(
        input, last_out, hebb, weight, ps, lr, out, hebb_new);
}